// Round 15
// baseline (607.448 us; speedup 1.0000x reference)
//
#include <hip/hip_runtime.h>
#include <stdint.h>

#define NRAYS   262144
#define NSAMP   256
#define RPB     16
#define TFINALF 1e10f
#define EPSF    1e-5f
#define CSTR    72     // cdf row stride (floats)
#define SSTR2   164    // half-staging row stride (floats)
#define SKEW    20     // sub-row skew (floats), 16B aligned

template<int CTRL>
__device__ __forceinline__ float dppf(float x) {
    return __int_as_float(__builtin_amdgcn_update_dpp(0, __float_as_int(x), CTRL, 0xF, 0xF, false));
}
template<int PAT>
__device__ __forceinline__ float swzf(float x) {
    return __int_as_float(__builtin_amdgcn_ds_swizzle(__float_as_int(x), PAT));
}
__device__ __forceinline__ float med3(float a, float b, float s) {
    return __builtin_amdgcn_fmed3f(a, b, s);
}

// inclusive +scan across each 16-lane row
__device__ __forceinline__ float row16_iscan(float x) {
    x += dppf<0x111>(x);
    x += dppf<0x112>(x);
    x += dppf<0x114>(x);
    x += dppf<0x118>(x);
    return x;
}

__device__ __forceinline__ void celo(float& a, float& b) {
    float mn = fminf(a, b), mx = fmaxf(a, b);
    a = mn; b = mx;
}

// cross-lane FLIP pass: partner = mirror-lane (CTRL), element 15-j.
template<int CTRL>
__device__ __forceinline__ void flipx(float w[16], float sel) {
#pragma unroll
    for (int p = 0; p < 8; ++p) {
        float a = w[p], b = w[15 - p];
        float oa = dppf<CTRL>(b);
        float ob = dppf<CTRL>(a);
        w[p]      = med3(a, oa, sel);
        w[15 - p] = med3(b, ob, sel);
    }
}

// cross-lane XOR pass, same element index
template<int CTRL>
__device__ __forceinline__ void jsx(float w[16], float sel) {
#pragma unroll
    for (int j = 0; j < 16; ++j)
        w[j] = med3(w[j], dppf<CTRL>(w[j]), sel);
}
// lane^4 via ds_swizzle
__device__ __forceinline__ void jsx_swz4(float w[16], float sel) {
#pragma unroll
    for (int j = 0; j < 16; ++j)
        w[j] = med3(w[j], swzf<0x101F>(w[j]), sel);
}

// in-lane min-low passes (static)
__device__ __forceinline__ void il_js8(float w[16]) {
#pragma unroll
    for (int j = 0; j < 8; ++j) celo(w[j], w[j + 8]);
}
__device__ __forceinline__ void il_js4(float w[16]) {
#pragma unroll
    for (int h = 0; h < 16; h += 8)
#pragma unroll
        for (int j = 0; j < 4; ++j) celo(w[h + j], w[h + j + 4]);
}
__device__ __forceinline__ void il_js2(float w[16]) {
#pragma unroll
    for (int h = 0; h < 16; h += 4) { celo(w[h], w[h + 2]); celo(w[h + 1], w[h + 3]); }
}
__device__ __forceinline__ void il_js1(float w[16]) {
#pragma unroll
    for (int j = 0; j < 16; j += 2) celo(w[j], w[j + 1]);
}

// normalized bitonic sort of 256 (16 lanes x 16 elems, e = lp*16 + j), ascending
__device__ __forceinline__ void sort256(float w[16], float s1, float s2m, float s4m, float s8m) {
    il_js1(w);
#pragma unroll
    for (int h = 0; h < 16; h += 4) { celo(w[h], w[h + 3]); celo(w[h + 1], w[h + 2]); }
    il_js1(w);
#pragma unroll
    for (int h = 0; h < 16; h += 8) {
        celo(w[h], w[h + 7]); celo(w[h + 1], w[h + 6]);
        celo(w[h + 2], w[h + 5]); celo(w[h + 3], w[h + 4]);
    }
    il_js2(w); il_js1(w);
#pragma unroll
    for (int j = 0; j < 8; ++j) celo(w[j], w[15 - j]);
    il_js4(w); il_js2(w); il_js1(w);
    flipx<0xB1>(w, s1);
    il_js8(w); il_js4(w); il_js2(w); il_js1(w);
    flipx<0x1B>(w, s2m);
    jsx<0xB1>(w, s1);
    il_js8(w); il_js4(w); il_js2(w); il_js1(w);
    flipx<0x141>(w, s4m);
    jsx<0x4E>(w, s2m);
    jsx<0xB1>(w, s1);
    il_js8(w); il_js4(w); il_js2(w); il_js1(w);
    flipx<0x140>(w, s8m);
    jsx_swz4(w, s4m);
    jsx<0x4E>(w, s2m);
    jsx<0xB1>(w, s1);
    il_js8(w); il_js4(w); il_js2(w); il_js1(w);
}

__global__ __launch_bounds__(256, 7) void informed_sampler_kernel(
    const float* __restrict__ tnear,
    const float* __restrict__ tfar,
    const float* __restrict__ dnorm,
    const float* __restrict__ density,
    const float* __restrict__ u,
    float* __restrict__ out)
{
    __shared__ float s_cdf[8 + RPB * CSTR];   // row c at 8 + c*72; row[i] = cdf[i+1]
    __shared__ float s2[RPB * SSTR2];         // half-staging

    const int tid  = threadIdx.x;
    const int lane = tid & 63;
    const int lp   = lane & 15;
    const int c    = tid >> 4;        // ray within block (0..15)
    const int r0   = blockIdx.x * RPB;
    const int r    = r0 + c;

    const float tn  = tnear[r];
    const float tff = tfar[r];
    const float dn  = dnorm[r];
    const float td  = tff - tn;
    const float inv63 = 1.0f / 63.0f;
    const float tdi = td * inv63;     // one coarse-bin width

    const float INF = __builtin_inff();
    const float s1  = (lane & 1) ? INF : -INF;
    const float s2m = (lane & 2) ? INF : -INF;
    const float s4m = (lane & 4) ? INF : -INF;
    const float s8m = (lane & 8) ? INF : -INF;

    // ---- load u: lane lp holds elements e = lp*16 + j ----
    const float4* ub = reinterpret_cast<const float4*>(u + (size_t)r * NSAMP);
    float w[16];
    {
        float4 a0 = ub[lp * 4 + 0], a1 = ub[lp * 4 + 1], a2 = ub[lp * 4 + 2], a3 = ub[lp * 4 + 3];
        w[ 0]=a0.x; w[ 1]=a0.y; w[ 2]=a0.z; w[ 3]=a0.w;
        w[ 4]=a1.x; w[ 5]=a1.y; w[ 6]=a1.z; w[ 7]=a1.w;
        w[ 8]=a2.x; w[ 9]=a2.y; w[10]=a2.z; w[11]=a2.w;
        w[12]=a3.x; w[13]=a3.y; w[14]=a3.z; w[15]=a3.w;
    }

    // ---- CDF build: lane lp owns bins b0..b0+3 ----
    const int b0 = lp * 4;
    float de0 = density[(size_t)(b0 + 0) * NRAYS + r];
    float de1 = density[(size_t)(b0 + 1) * NRAYS + r];
    float de2 = density[(size_t)(b0 + 2) * NRAYS + r];
    float de3 = density[(size_t)(b0 + 3) * NRAYS + r];

    float dl3 = (lp == 15) ? (TFINALF - (tn + td)) : tdi;
    float sd0 = de0 * tdi * dn, sd1 = de1 * tdi * dn, sd2 = de2 * tdi * dn, sd3 = de3 * dl3 * dn;

    float p0 = sd0, p1 = p0 + sd1, p2 = p1 + sd2, p3 = p2 + sd3;
    float tsc   = row16_iscan(p3);
    float carry = dppf<0x111>(tsc);              // exclusive lane-carry (lane0 -> 0, no cancellation)
    float x0 = carry, x1 = carry + p0, x2 = carry + p1, x3 = carry + p2, x4 = carry + p3;
    float e0 = __expf(-x0), e1 = __expf(-x1), e2 = __expf(-x2), e3 = __expf(-x3), e4 = __expf(-x4);
    float wv0 = e0 - e1 + EPSF, wv1 = e1 - e2 + EPSF, wv2 = e2 - e3 + EPSF, wv3 = e3 - e4 + EPSF;
    float q0 = wv0, q1 = q0 + wv1, q2 = q1 + wv2, q3 = q2 + wv3;
    float tww = row16_iscan(q3);
    float cw  = dppf<0x111>(tww);
    float tot = swzf<0x1F0>(tww);                // bcast lane15 of 16-group
    float inv = __builtin_amdgcn_rcpf(tot);

    float rv0 = (cw + q0) * inv, rv1 = (cw + q1) * inv,
          rv2 = (cw + q2) * inv, rv3 = (cw + q3) * inv;   // row[b0..b0+3]
    float* cdfrow = &s_cdf[8 + c * CSTR];
    *reinterpret_cast<float4*>(cdfrow + b0) = make_float4(rv0, rv1, rv2, rv3);

    // probe-tree upper levels in registers (rv3 of odd lanes)
    float r7  = swzf<0x030>(rv3);
    float r15 = swzf<0x070>(rv3);
    float r23 = swzf<0x0B0>(rv3);
    float r31 = swzf<0x0F0>(rv3);
    float r39 = swzf<0x130>(rv3);
    float r47 = swzf<0x170>(rv3);
    float r55 = swzf<0x1B0>(rv3);

    // ---- sort u ascending across the 16-lane group (pure VALU/DPP med3;
    //      overlaps the cdf store latency) ----
    sort256(w, s1, s2m, s4m, s8m);

    __asm__ volatile("s_waitcnt lgkmcnt(0)" ::: "memory");  // cdf visible

    // ---- inverse-CDF: 3 register levels + 1 LDS probe + 1 b128 quad fetch ----
    //      cin carries row[b-1] (last accepted probe); chain is 2 DS links deep.
#pragma unroll
    for (int j = 0; j < 16; ++j) {
        float uq = w[j];
        float cin = 0.0f;                     // row[-1] := cdf[0] = 0
        bool  a32 = (r31 <= uq);
        int   b   = a32 ? 32 : 0;
        cin = a32 ? r31 : cin;
        float p16 = a32 ? r47 : r15;
        bool  a16 = (p16 <= uq);
        b += a16 ? 16 : 0;
        cin = a16 ? p16 : cin;
        float pA = a32 ? r39 : r7;
        float pB = a32 ? r55 : r23;
        float p8 = a16 ? pB : pA;
        bool  a8 = (p8 <= uq);
        b += a8 ? 8 : 0;
        cin = a8 ? p8 : cin;
        float p4 = cdfrow[b + 3];             // LDS probe (level 4)
        bool  a4 = (p4 <= uq);
        b += a4 ? 4 : 0;
        cin = a4 ? p4 : cin;
        float4 v = *reinterpret_cast<const float4*>(cdfrow + b);  // row[b..b+3], 16B aligned
        int cnt = (int)(v.x <= uq) + (int)(v.y <= uq) + (int)(v.z <= uq);
        float cb = (cnt == 0) ? cin : ((cnt == 1) ? v.x : ((cnt == 2) ? v.y : v.z));
        float ca = (cnt == 0) ? v.x : ((cnt == 1) ? v.y : ((cnt == 2) ? v.z : v.w));
        b += cnt;
        float dnm = ca - cb;
        dnm = (dnm < EPSF) ? 1.0f : dnm;
        float fb = (float)b;
        float eb = fmaf(fmaxf(fb - 0.5f, 0.0f), tdi, tn);   // exact at b=0
        float ea = fmaf(fminf(fb + 0.5f, 63.0f), tdi, tn);  // exact at b=63
        float smp = eb + (uq - cb) * __builtin_amdgcn_rcpf(dnm) * (ea - eb);
        w[j] = med3(smp, tn, tff);            // clamp idiom: 1 instr, exact bounds
    }

    // ---- two-phase transposed output (half-size staging) ----
    float* s2row = &s2[c * SSTR2];
    const int g16 = tid >> 4;       // == c
    const int cc  = tid & 15;

    if (lp < 8) {                    // ranks 0..127
#pragma unroll
        for (int q = 0; q < 4; ++q)
            *reinterpret_cast<float4*>(&s2row[lp * SKEW + q * 4]) =
                make_float4(w[4 * q], w[4 * q + 1], w[4 * q + 2], w[4 * q + 3]);
    }
    __syncthreads();
#pragma unroll
    for (int it = 0; it < 8; ++it) {
        int s = it * 16 + g16;
        out[(size_t)s * NRAYS + r0 + cc] = s2[cc * SSTR2 + it * SKEW + g16];
    }
    __syncthreads();
    if (lp >= 8) {                   // ranks 128..255
#pragma unroll
        for (int q = 0; q < 4; ++q)
            *reinterpret_cast<float4*>(&s2row[(lp - 8) * SKEW + q * 4]) =
                make_float4(w[4 * q], w[4 * q + 1], w[4 * q + 2], w[4 * q + 3]);
    }
    __syncthreads();
#pragma unroll
    for (int it = 0; it < 8; ++it) {
        int s = 128 + it * 16 + g16;
        out[(size_t)s * NRAYS + r0 + cc] = s2[cc * SSTR2 + it * SKEW + g16];
    }
}

extern "C" void kernel_launch(void* const* d_in, const int* in_sizes, int n_in,
                              void* d_out, int out_size, void* d_ws, size_t ws_size,
                              hipStream_t stream) {
    const float* tnear   = (const float*)d_in[0];
    const float* tfar    = (const float*)d_in[1];
    const float* dnorm   = (const float*)d_in[2];
    const float* density = (const float*)d_in[3];
    const float* u       = (const float*)d_in[4];
    float* out = (float*)d_out;

    dim3 grid(NRAYS / RPB);
    dim3 block(256);
    hipLaunchKernelGGL(informed_sampler_kernel, grid, block, 0, stream,
                       tnear, tfar, dnorm, density, u, out);
}

// Round 16
// 192.562 us; speedup vs baseline: 3.1545x; 3.1545x over previous
//
#include <hip/hip_runtime.h>
#include <stdint.h>

#define NRAYS   262144
#define NSAMP   256
#define RPB     16
#define TFINALF 1e10f
#define EPSF    1e-5f
#define CSTR    72     // cdf row stride (floats)
#define SSTR2   164    // half-staging row stride (floats)
#define SKEW    20     // sub-row skew (floats), 16B aligned

template<int CTRL>
__device__ __forceinline__ float dppf(float x) {
    return __int_as_float(__builtin_amdgcn_update_dpp(0, __float_as_int(x), CTRL, 0xF, 0xF, false));
}
template<int PAT>
__device__ __forceinline__ float swzf(float x) {
    return __int_as_float(__builtin_amdgcn_ds_swizzle(__float_as_int(x), PAT));
}
__device__ __forceinline__ float med3(float a, float b, float s) {
    return __builtin_amdgcn_fmed3f(a, b, s);
}

// inclusive +scan across each 16-lane row
__device__ __forceinline__ float row16_iscan(float x) {
    x += dppf<0x111>(x);
    x += dppf<0x112>(x);
    x += dppf<0x114>(x);
    x += dppf<0x118>(x);
    return x;
}

__device__ __forceinline__ void celo(float& a, float& b) {
    float mn = fminf(a, b), mx = fmaxf(a, b);
    a = mn; b = mx;
}

// cross-lane FLIP pass: partner = mirror-lane (CTRL), element 15-j.
// sel = +INF on max-keeping lanes, -INF on min-keeping: fmed3 does the keep in 1 op.
template<int CTRL>
__device__ __forceinline__ void flipx(float w[16], float sel) {
#pragma unroll
    for (int p = 0; p < 8; ++p) {
        float a = w[p], b = w[15 - p];
        float oa = dppf<CTRL>(b);   // partner lane's w[15-p]
        float ob = dppf<CTRL>(a);   // partner lane's w[p]
        w[p]      = med3(a, oa, sel);
        w[15 - p] = med3(b, ob, sel);
    }
}

// cross-lane XOR pass, same element index
template<int CTRL>
__device__ __forceinline__ void jsx(float w[16], float sel) {
#pragma unroll
    for (int j = 0; j < 16; ++j)
        w[j] = med3(w[j], dppf<CTRL>(w[j]), sel);
}
// lane^4 via ds_swizzle
__device__ __forceinline__ void jsx_swz4(float w[16], float sel) {
#pragma unroll
    for (int j = 0; j < 16; ++j)
        w[j] = med3(w[j], swzf<0x101F>(w[j]), sel);
}

// in-lane min-low passes (static)
__device__ __forceinline__ void il_js8(float w[16]) {
#pragma unroll
    for (int j = 0; j < 8; ++j) celo(w[j], w[j + 8]);
}
__device__ __forceinline__ void il_js4(float w[16]) {
#pragma unroll
    for (int h = 0; h < 16; h += 8)
#pragma unroll
        for (int j = 0; j < 4; ++j) celo(w[h + j], w[h + j + 4]);
}
__device__ __forceinline__ void il_js2(float w[16]) {
#pragma unroll
    for (int h = 0; h < 16; h += 4) { celo(w[h], w[h + 2]); celo(w[h + 1], w[h + 3]); }
}
__device__ __forceinline__ void il_js1(float w[16]) {
#pragma unroll
    for (int j = 0; j < 16; j += 2) celo(w[j], w[j + 1]);
}

// normalized bitonic sort of 256 (16 lanes x 16 elems, e = lp*16 + j), ascending
__device__ __forceinline__ void sort256(float w[16], float s1, float s2m, float s4m, float s8m) {
    il_js1(w);
#pragma unroll
    for (int h = 0; h < 16; h += 4) { celo(w[h], w[h + 3]); celo(w[h + 1], w[h + 2]); }
    il_js1(w);
#pragma unroll
    for (int h = 0; h < 16; h += 8) {
        celo(w[h], w[h + 7]); celo(w[h + 1], w[h + 6]);
        celo(w[h + 2], w[h + 5]); celo(w[h + 3], w[h + 4]);
    }
    il_js2(w); il_js1(w);
#pragma unroll
    for (int j = 0; j < 8; ++j) celo(w[j], w[15 - j]);
    il_js4(w); il_js2(w); il_js1(w);
    flipx<0xB1>(w, s1);
    il_js8(w); il_js4(w); il_js2(w); il_js1(w);
    flipx<0x1B>(w, s2m);
    jsx<0xB1>(w, s1);
    il_js8(w); il_js4(w); il_js2(w); il_js1(w);
    flipx<0x141>(w, s4m);
    jsx<0x4E>(w, s2m);
    jsx<0xB1>(w, s1);
    il_js8(w); il_js4(w); il_js2(w); il_js1(w);
    flipx<0x140>(w, s8m);
    jsx_swz4(w, s4m);
    jsx<0x4E>(w, s2m);
    jsx<0xB1>(w, s1);
    il_js8(w); il_js4(w); il_js2(w); il_js1(w);
}

__global__ __launch_bounds__(256, 7) void informed_sampler_kernel(
    const float* __restrict__ tnear,
    const float* __restrict__ tfar,
    const float* __restrict__ dnorm,
    const float* __restrict__ density,
    const float* __restrict__ u,
    float* __restrict__ out)
{
    __shared__ float s_cdf[8 + RPB * CSTR];   // row c at 8 + c*72; row[i] = cdf[i+1]
    __shared__ float s2[RPB * SSTR2];         // half-staging

    const int tid  = threadIdx.x;
    const int lane = tid & 63;
    const int lp   = lane & 15;
    const int c    = tid >> 4;        // ray within block (0..15)
    const int r0   = blockIdx.x * RPB;
    const int r    = r0 + c;

    const float tn  = tnear[r];
    const float tff = tfar[r];
    const float dn  = dnorm[r];
    const float td  = tff - tn;
    const float inv63 = 1.0f / 63.0f;
    const float tdi = td * inv63;     // one coarse-bin width

    const float INF = __builtin_inff();
    const float s1  = (lane & 1) ? INF : -INF;
    const float s2m = (lane & 2) ? INF : -INF;
    const float s4m = (lane & 4) ? INF : -INF;
    const float s8m = (lane & 8) ? INF : -INF;

    // ---- load u: lane lp holds elements e = lp*16 + j ----
    const float4* ub = reinterpret_cast<const float4*>(u + (size_t)r * NSAMP);
    float w[16];
    {
        float4 a0 = ub[lp * 4 + 0], a1 = ub[lp * 4 + 1], a2 = ub[lp * 4 + 2], a3 = ub[lp * 4 + 3];
        w[ 0]=a0.x; w[ 1]=a0.y; w[ 2]=a0.z; w[ 3]=a0.w;
        w[ 4]=a1.x; w[ 5]=a1.y; w[ 6]=a1.z; w[ 7]=a1.w;
        w[ 8]=a2.x; w[ 9]=a2.y; w[10]=a2.z; w[11]=a2.w;
        w[12]=a3.x; w[13]=a3.y; w[14]=a3.z; w[15]=a3.w;
    }

    // ---- CDF build: lane lp owns bins b0..b0+3 ----
    const int b0 = lp * 4;
    float de0 = density[(size_t)(b0 + 0) * NRAYS + r];
    float de1 = density[(size_t)(b0 + 1) * NRAYS + r];
    float de2 = density[(size_t)(b0 + 2) * NRAYS + r];
    float de3 = density[(size_t)(b0 + 3) * NRAYS + r];

    float dl3 = (lp == 15) ? (TFINALF - (tn + td)) : tdi;
    float sd0 = de0 * tdi * dn, sd1 = de1 * tdi * dn, sd2 = de2 * tdi * dn, sd3 = de3 * dl3 * dn;

    float p0 = sd0, p1 = p0 + sd1, p2 = p1 + sd2, p3 = p2 + sd3;
    float tsc   = row16_iscan(p3);
    float carry = dppf<0x111>(tsc);              // exclusive lane-carry (lane0 -> 0, no cancellation)
    float x0 = carry, x1 = carry + p0, x2 = carry + p1, x3 = carry + p2, x4 = carry + p3;
    float e0 = __expf(-x0), e1 = __expf(-x1), e2 = __expf(-x2), e3 = __expf(-x3), e4 = __expf(-x4);
    float wv0 = e0 - e1 + EPSF, wv1 = e1 - e2 + EPSF, wv2 = e2 - e3 + EPSF, wv3 = e3 - e4 + EPSF;
    float q0 = wv0, q1 = q0 + wv1, q2 = q1 + wv2, q3 = q2 + wv3;
    float tww = row16_iscan(q3);
    float cw  = dppf<0x111>(tww);
    float tot = swzf<0x1F0>(tww);                // bcast lane15 of 16-group
    float inv = __builtin_amdgcn_rcpf(tot);

    float rv0 = (cw + q0) * inv, rv1 = (cw + q1) * inv,
          rv2 = (cw + q2) * inv, rv3 = (cw + q3) * inv;   // row[b0..b0+3]
    float* cdfrow = &s_cdf[8 + c * CSTR];
    *reinterpret_cast<float4*>(cdfrow + b0) = make_float4(rv0, rv1, rv2, rv3);

    // probe-tree upper levels in registers (rv3 of odd lanes)
    float r7  = swzf<0x030>(rv3);
    float r15 = swzf<0x070>(rv3);
    float r23 = swzf<0x0B0>(rv3);
    float r31 = swzf<0x0F0>(rv3);
    float r39 = swzf<0x130>(rv3);
    float r47 = swzf<0x170>(rv3);
    float r55 = swzf<0x1B0>(rv3);

    // ---- sort u ascending across the 16-lane group (pure VALU/DPP med3;
    //      overlaps the cdf store latency) ----
    sort256(w, s1, s2m, s4m, s8m);

    __asm__ volatile("s_waitcnt lgkmcnt(0)" ::: "memory");  // cdf visible

    // ---- inverse-CDF: 3 register levels + 3 clustered LDS probes + read2 pair ----
#pragma unroll
    for (int j = 0; j < 16; ++j) {
        float uq = w[j];
        bool  c32 = (r31 <= uq);
        int   b   = c32 ? 32 : 0;
        float p16 = c32 ? r47 : r15;
        bool  t16 = (p16 <= uq);
        b += t16 ? 16 : 0;
        float pA = c32 ? r39 : r7;
        float pB = c32 ? r55 : r23;
        float p8 = t16 ? pB : pA;
        b += (p8 <= uq) ? 8 : 0;
        if (cdfrow[b + 3] <= uq) b += 4;
        if (cdfrow[b + 1] <= uq) b += 2;
        if (cdfrow[b]     <= uq) b += 1;
        float cbm = cdfrow[b - 1];       // adjacent pair -> ds_read2_b32
        float ca  = cdfrow[b];
        float cb  = (b == 0) ? 0.0f : cbm;
        float dnm = ca - cb;
        dnm = (dnm < EPSF) ? 1.0f : dnm;
        float fb = (float)b;
        float eb = fmaf(fmaxf(fb - 0.5f, 0.0f), tdi, tn);   // exact at b=0
        float ea = fmaf(fminf(fb + 0.5f, 63.0f), tdi, tn);  // exact at b=63
        float smp = eb + (uq - cb) * __builtin_amdgcn_rcpf(dnm) * (ea - eb);
        w[j] = med3(smp, tn, tff);       // clamp idiom: 1 instr, exact bounds
    }

    // ---- two-phase transposed output (half-size staging) ----
    float* s2row = &s2[c * SSTR2];
    const int g16 = tid >> 4;       // == c
    const int cc  = tid & 15;

    if (lp < 8) {                    // ranks 0..127
#pragma unroll
        for (int q = 0; q < 4; ++q)
            *reinterpret_cast<float4*>(&s2row[lp * SKEW + q * 4]) =
                make_float4(w[4 * q], w[4 * q + 1], w[4 * q + 2], w[4 * q + 3]);
    }
    __syncthreads();
#pragma unroll
    for (int it = 0; it < 8; ++it) {
        int s = it * 16 + g16;
        out[(size_t)s * NRAYS + r0 + cc] = s2[cc * SSTR2 + it * SKEW + g16];
    }
    __syncthreads();
    if (lp >= 8) {                   // ranks 128..255
#pragma unroll
        for (int q = 0; q < 4; ++q)
            *reinterpret_cast<float4*>(&s2row[(lp - 8) * SKEW + q * 4]) =
                make_float4(w[4 * q], w[4 * q + 1], w[4 * q + 2], w[4 * q + 3]);
    }
    __syncthreads();
#pragma unroll
    for (int it = 0; it < 8; ++it) {
        int s = 128 + it * 16 + g16;
        out[(size_t)s * NRAYS + r0 + cc] = s2[cc * SSTR2 + it * SKEW + g16];
    }
}

extern "C" void kernel_launch(void* const* d_in, const int* in_sizes, int n_in,
                              void* d_out, int out_size, void* d_ws, size_t ws_size,
                              hipStream_t stream) {
    const float* tnear   = (const float*)d_in[0];
    const float* tfar    = (const float*)d_in[1];
    const float* dnorm   = (const float*)d_in[2];
    const float* density = (const float*)d_in[3];
    const float* u       = (const float*)d_in[4];
    float* out = (float*)d_out;

    dim3 grid(NRAYS / RPB);
    dim3 block(256);
    hipLaunchKernelGGL(informed_sampler_kernel, grid, block, 0, stream,
                       tnear, tfar, dnorm, density, u, out);
}